// Round 5
// baseline (122.170 us; speedup 1.0000x reference)
//
#include <hip/hip_runtime.h>

// ============================================================================
// 7-layer MLP (3->40x6->3, tanh) via f16 MFMA + LDS tanh lookup table.
//
// MFMA layout contracts (gfx950 v_mfma_f32_32x32x16_f16), verified in r3:
//   A (M=32 x K=16): row = lane&31, k = 8*(lane>>5) + i, i=0..7
//   B (K=16 x N=32): col = lane&31, k = 8*(lane>>5) + i   (same packing)
//   D (M=32 x N=32): col = lane&31, row = (reg&3) + 8*(reg>>2) + 4*(lane>>5)
// Activations are X^T (features x points); K-columns of every weight matrix
// are permuted (kappa) so D->B repack is pure in-lane.
//
// tanh table (r5): entries packed f16 {base, delta} in ONE u32, 16-way lane
// replicated (4 lanes/slot over 2 banks -> ~2-way = free, vs r4's 2e7
// conflict cycles). Hidden weights pre-scaled by 1/h and +192 offset column
// so MFMA emits table coord u directly. Lookup: med3, fract, cvt, ds_read_b32,
// v_fma_mixlo/hi_f16 (writes the f16 activation straight into the B-fragment
// half-word -> no cvt_pkrtz, no f32 fma).
// ============================================================================

typedef _Float16 f16x8 __attribute__((ext_vector_type(8)));
typedef float    f32x16 __attribute__((ext_vector_type(16)));
typedef unsigned int u32x4 __attribute__((ext_vector_type(4)));

#define NFRAG  35        // L0: 2, L1..5: 6 each, L6: 3.  1 frag = 64 lanes x 16 B
#define TABN   385       // table entries (384 intervals)
#define TABREP 16        // lane replication (u32 entries)
#define TABH   0.025f
#define INVH   40.0f     // 1/TABH
#define TABR   4.8f      // domain [-R, R]
#define UOFF   192.0f    // R/h, exact in f16
#define UMAX   383.999f

// k-slot -> input neuron; -2 = bias (x 1/h), -3 = +192 const, -1 = zero pad
__constant__ int INV[48] = {
     0,  1,  2,  3,   8,  9, 10, 11,   4,  5,  6,  7,  12, 13, 14, 15,
    16, 17, 18, 19,  24, 25, 26, 27,  20, 21, 22, 23,  28, 29, 30, 31,
    32, 33, 34, 35,  -1, -1, -1, -1,  36, 37, 38, 39,  -2, -3, -1, -1 };

__global__ void prep_frags(const float* __restrict__ W0, const float* __restrict__ b0,
                           const float* __restrict__ W1, const float* __restrict__ b1,
                           const float* __restrict__ W2, const float* __restrict__ b2,
                           const float* __restrict__ W3, const float* __restrict__ b3,
                           const float* __restrict__ W4, const float* __restrict__ b4,
                           const float* __restrict__ W5, const float* __restrict__ b5,
                           const float* __restrict__ W6, const float* __restrict__ b6,
                           unsigned short* __restrict__ frags,
                           unsigned* __restrict__ table)
{
    int tid = blockIdx.x * 256 + threadIdx.x;

    if (tid < NFRAG * 64) {
        int frag = tid >> 6, lane = tid & 63;

        int layer, mt, ch;
        if (frag < 2)       { layer = 0; mt = frag; ch = 0; }
        else if (frag < 32) { int t = frag - 2; layer = 1 + t / 6; int r = t % 6; mt = r / 3; ch = r % 3; }
        else                { layer = 6; mt = 0; ch = frag - 32; }

        const float* Ws[7] = { W0, W1, W2, W3, W4, W5, W6 };
        const float* bs[7] = { b0, b1, b2, b3, b4, b5, b6 };
        const float* W = Ws[layer];
        const float* b = bs[layer];
        const int fout = (layer == 6) ? 3 : 40;
        const float scale = (layer == 6) ? 1.0f : INVH;   // final layer: true output

        int jout  = mt * 32 + (lane & 31);
        int kbase = ch * 16 + (lane >> 5) * 8;

        unsigned short h[8];
        for (int i = 0; i < 8; ++i) {
            int k = kbase + i;
            float v = 0.0f;
            if (jout < fout) {
                int jin;
                if (layer == 0) jin = (k < 3) ? k : ((k == 3) ? -2 : ((k == 4) ? -3 : -1));
                else            jin = INV[k];
                if (jin >= 0)       v = W[jin * fout + jout] * scale;
                else if (jin == -2) v = b[jout] * scale;
                else if (jin == -3) v = (layer == 6) ? 0.0f : UOFF;
            }
            _Float16 hv = (_Float16)v;
            h[i] = __builtin_bit_cast(unsigned short, hv);
        }
        unsigned short* dst = frags + frag * 512 + lane * 8;
        for (int i = 0; i < 8; ++i) dst[i] = h[i];
    }
    else if (tid < NFRAG * 64 + TABN) {
        int i = tid - NFRAG * 64;
        float x  = -TABR + (float)i * TABH;
        float t0 = tanhf(x);
        float t1 = tanhf(x + TABH);
        unsigned short bb = __builtin_bit_cast(unsigned short, (_Float16)t0);
        unsigned short dd = __builtin_bit_cast(unsigned short, (_Float16)(t1 - t0));
        unsigned e = (unsigned)bb | ((unsigned)dd << 16);
        for (int r = 0; r < TABREP; ++r) table[i * TABREP + r] = e;
    }
}

__device__ __forceinline__ unsigned int pkf16(float a, float b) {
    return __builtin_bit_cast(unsigned int, __builtin_amdgcn_cvt_pkrtz(a, b));
}
__device__ __forceinline__ f32x16 zf() {
    f32x16 v;
    #pragma unroll
    for (int i = 0; i < 16; ++i) v[i] = 0.0f;
    return v;
}

#define MFMA __builtin_amdgcn_mfma_f32_32x32x16_f16

// D holds table coords; lookup two tanhs, pack results as f16 pair in one u32
#define ACT(Da, Db) do {                              \
    Bf[0]  = tl2(Da[0],  Da[1]);                      \
    Bf[1]  = tl2(Da[2],  Da[3]);                      \
    Bf[2]  = tl2(Da[4],  Da[5]);                      \
    Bf[3]  = tl2(Da[6],  Da[7]);                      \
    Bf[4]  = tl2(Da[8],  Da[9]);                      \
    Bf[5]  = tl2(Da[10], Da[11]);                     \
    Bf[6]  = tl2(Da[12], Da[13]);                     \
    Bf[7]  = tl2(Da[14], Da[15]);                     \
    Bf[8]  = tl2(Db[0],  Db[1]);                      \
    Bf[9]  = tl2(Db[2],  Db[3]);                      \
    Bf[10] = PK11;                                    \
    Bf[11] = 0u;                                      \
} while (0)

__global__ __launch_bounds__(512, 4) void mlp_mfma(const float* __restrict__ coords,
                                                   const unsigned short* __restrict__ frags,
                                                   const unsigned* __restrict__ gtab,
                                                   float* __restrict__ out, int npts)
{
    __shared__ __align__(16) unsigned short sf[NFRAG * 512];      // 35840 B
    __shared__ __align__(16) unsigned stab[TABN * TABREP];        // 24640 B
    {
        const u32x4* s1 = (const u32x4*)frags; u32x4* d1 = (u32x4*)sf;
        for (int i = threadIdx.x; i < NFRAG * 64; i += 512) d1[i] = s1[i];
        const u32x4* s2 = (const u32x4*)gtab;  u32x4* d2 = (u32x4*)stab;
        for (int i = threadIdx.x; i < TABN * TABREP / 4; i += 512) d2[i] = s2[i];
    }
    __syncthreads();

    const int lane = threadIdx.x & 63;
    const int wid  = threadIdx.x >> 6;
    const int p    = (blockIdx.x * 8 + wid) * 32 + (lane & 31);
    const bool valid = (p < npts);

    float c0 = 0.f, c1 = 0.f, c2 = 0.f;
    if (valid) { c0 = coords[p * 3]; c1 = coords[p * 3 + 1]; c2 = coords[p * 3 + 2]; }

    const unsigned int PK11 = pkf16(1.0f, 1.0f);
    const unsigned* __restrict__ tb = stab + (lane & (TABREP - 1));   // lane replica base
    const f32x16 CZ = zf();   // hoisted zero-C for MFMA acc init

    // two tanh lookups -> packed f16 pair (lo = ua's tanh, hi = ub's tanh).
    // v_fma_mixlo/hi_f16: f32 fr times f16 delta (entry hi) plus f16 base
    // (entry lo), rounded to f16 into the selected half of the dest.
    auto tl2 = [&](float ua, float ub) -> unsigned {
        ua = __builtin_amdgcn_fmed3f(ua, 0.0f, UMAX);
        ub = __builtin_amdgcn_fmed3f(ub, 0.0f, UMAX);
        float fa = __builtin_amdgcn_fractf(ua);
        float fb = __builtin_amdgcn_fractf(ub);
        unsigned ea = tb[(unsigned)ua * TABREP];   // ds_read_b32
        unsigned eb = tb[(unsigned)ub * TABREP];   // ds_read_b32
        unsigned r;
        asm("v_fma_mixlo_f16 %0, %1, %2, %2 op_sel:[0,1,0] op_sel_hi:[0,1,1]"
            : "=v"(r) : "v"(fa), "v"(ea));
        asm("v_fma_mixhi_f16 %0, %1, %2, %2 op_sel:[0,1,0] op_sel_hi:[0,1,1]"
            : "+v"(r) : "v"(fb), "v"(eb));
        return r;
    };

    unsigned int Bf[12];
    Bf[0] = pkf16(c0, c1);
    Bf[1] = pkf16(c2, 1.0f);      // k=3: bias/h column
    Bf[2] = pkf16(1.0f, 0.0f);    // k=4: +192 const column
    Bf[3] = 0u;

    auto AF = [&](int f) -> f16x8 {
        return ((const f16x8*)sf)[f * 64 + lane];
    };
    auto BF = [&](int c) -> f16x8 {
        u32x4 t = { Bf[4 * c + 0], Bf[4 * c + 1], Bf[4 * c + 2], Bf[4 * c + 3] };
        return __builtin_bit_cast(f16x8, t);
    };

    // ---- layer 0 (K chunk 0 only: coords + bias + offset cols)
    {
        f16x8 bb = BF(0);
        f32x16 D0 = MFMA(AF(0), bb, CZ, 0, 0, 0);
        f32x16 D1 = MFMA(AF(1), bb, CZ, 0, 0, 0);
        ACT(D0, D1);
    }

    // ---- hidden layers 1..5
    #pragma unroll
    for (int l = 1; l <= 5; ++l) {
        const int fb = 2 + (l - 1) * 6;
        f16x8 bc0 = BF(0), bc1 = BF(1), bc2 = BF(2);
        f32x16 D0 = MFMA(AF(fb + 0), bc0, CZ, 0, 0, 0);
        D0 = MFMA(AF(fb + 1), bc1, D0, 0, 0, 0);
        D0 = MFMA(AF(fb + 2), bc2, D0, 0, 0, 0);
        f32x16 D1 = MFMA(AF(fb + 3), bc0, CZ, 0, 0, 0);
        D1 = MFMA(AF(fb + 4), bc1, D1, 0, 0, 0);
        D1 = MFMA(AF(fb + 5), bc2, D1, 0, 0, 0);
        ACT(D0, D1);
    }

    // ---- layer 6: [40] -> [3], true scale, no tanh. Outputs rows 0..2.
    {
        f32x16 D0 = MFMA(AF(32), BF(0), CZ, 0, 0, 0);
        D0 = MFMA(AF(33), BF(1), D0, 0, 0, 0);
        D0 = MFMA(AF(34), BF(2), D0, 0, 0, 0);
        if (lane < 32 && valid) {
            out[p * 3 + 0] = D0[0];
            out[p * 3 + 1] = D0[1];
            out[p * 3 + 2] = D0[2];
        }
    }
}

extern "C" void kernel_launch(void* const* d_in, const int* in_sizes, int n_in,
                              void* d_out, int out_size, void* d_ws, size_t ws_size,
                              hipStream_t stream)
{
    const float* coords = (const float*)d_in[0];
    const float* W0 = (const float*)d_in[1];  const float* b0 = (const float*)d_in[2];
    const float* W1 = (const float*)d_in[3];  const float* b1 = (const float*)d_in[4];
    const float* W2 = (const float*)d_in[5];  const float* b2 = (const float*)d_in[6];
    const float* W3 = (const float*)d_in[7];  const float* b3 = (const float*)d_in[8];
    const float* W4 = (const float*)d_in[9];  const float* b4 = (const float*)d_in[10];
    const float* W5 = (const float*)d_in[11]; const float* b5 = (const float*)d_in[12];
    const float* W6 = (const float*)d_in[13]; const float* b6 = (const float*)d_in[14];
    float* out = (float*)d_out;

    unsigned short* frags = (unsigned short*)d_ws;                      // 35840 B
    unsigned* table = (unsigned*)((char*)d_ws + NFRAG * 1024);          // 24640 B

    const int npts = in_sizes[0] / 3;

    const int prep_threads = NFRAG * 64 + TABN;
    prep_frags<<<(prep_threads + 255) / 256, 256, 0, stream>>>(
        W0, b0, W1, b1, W2, b2, W3, b3, W4, b4, W5, b5, W6, b6, frags, table);

    const int blocks = (npts + 255) / 256;   // 256 points per block (8 waves x 32)
    mlp_mfma<<<blocks, 512, 0, stream>>>(coords, frags, table, out, npts);
}

// Round 7
// 118.847 us; speedup vs baseline: 1.0280x; 1.0280x over previous
//
#include <hip/hip_runtime.h>

// ============================================================================
// 7-layer MLP (3->40x6->3, tanh) via f16 MFMA + conflict-free LDS tanh table.
//
// MFMA layout contracts (gfx950 v_mfma_f32_32x32x16_f16), verified r3-r5:
//   A: row = lane&31, k = 8*(lane>>5)+i   B: col = lane&31, same k packing
//   D: col = lane&31, row = (reg&3) + 8*(reg>>2) + 4*(lane>>5)
// K-columns of every weight matrix permuted (kappa) so D->B repack is
// in-lane. Weights pre-scaled by 1/h=32 with +112 offset column so the MFMA
// emits the table coordinate u = (x+3.5)*32 directly.
//
// Table: 225 entries (domain +-3.5, h=1/32), packed f16 {base,delta} per u32.
// Stored UNREPLICATED in ws (900 B -> ws total 36.7 KB, r3-r5-proven range;
// r6's 64.6 KB ws use is a suspected overflow). Replicated 32x at LDS staging
// so read address = idx*32 + (lane&31) -> bank == lane&31 -> conflict-free
// (lane/lane+32 2-way is free, m136). Edge entries biased to the saturation
// midpoint: clamp error (1-tanh(3.5))/2 = 9.1e-4.
// 64 points per wave (two N=32 B-tiles) amortizes the 35 ds_read_b128 weight
// fragment reads. r5 model: LDS pipe 100% busy was the wall (1356cyc/wave
// x 256 waves/CU = 145us = measured); new model 1812cyc x 128 waves = ~97us.
// ============================================================================

typedef _Float16 f16x8 __attribute__((ext_vector_type(8)));
typedef float    f32x16 __attribute__((ext_vector_type(16)));
typedef unsigned int u32x4 __attribute__((ext_vector_type(4)));

#define NFRAG  35        // L0: 2, L1..5: 6 each, L6: 3
#define TABN   225       // entries, domain [-3.5, 3.5], h = 1/32
#define TABREP 32        // LDS replication -> bank = lane&31, conflict-free
#define INVH   32.0f
#define UOFF   112.0f    // 3.5*32, exact in f16
#define UMAX   223.999f
#define TABR   3.5f

// k-slot -> input neuron; -2 = bias, -3 = offset const, -1 = zero pad
__constant__ int INV[48] = {
     0,  1,  2,  3,   8,  9, 10, 11,   4,  5,  6,  7,  12, 13, 14, 15,
    16, 17, 18, 19,  24, 25, 26, 27,  20, 21, 22, 23,  28, 29, 30, 31,
    32, 33, 34, 35,  -1, -1, -1, -1,  36, 37, 38, 39,  -2, -3, -1, -1 };

__global__ void prep_frags(const float* __restrict__ W0, const float* __restrict__ b0,
                           const float* __restrict__ W1, const float* __restrict__ b1,
                           const float* __restrict__ W2, const float* __restrict__ b2,
                           const float* __restrict__ W3, const float* __restrict__ b3,
                           const float* __restrict__ W4, const float* __restrict__ b4,
                           const float* __restrict__ W5, const float* __restrict__ b5,
                           const float* __restrict__ W6, const float* __restrict__ b6,
                           unsigned short* __restrict__ frags,
                           unsigned* __restrict__ table)
{
    int tid = blockIdx.x * 256 + threadIdx.x;

    if (tid < NFRAG * 64) {
        int frag = tid >> 6, lane = tid & 63;

        int layer, mt, ch;
        if (frag < 2)       { layer = 0; mt = frag; ch = 0; }
        else if (frag < 32) { int t = frag - 2; layer = 1 + t / 6; int r = t % 6; mt = r / 3; ch = r % 3; }
        else                { layer = 6; mt = 0; ch = frag - 32; }

        const float* Ws[7] = { W0, W1, W2, W3, W4, W5, W6 };
        const float* bs[7] = { b0, b1, b2, b3, b4, b5, b6 };
        const float* W = Ws[layer];
        const float* b = bs[layer];
        const int fout = (layer == 6) ? 3 : 40;
        const float scale = (layer == 6) ? 1.0f : INVH;

        int jout  = mt * 32 + (lane & 31);
        int kbase = ch * 16 + (lane >> 5) * 8;

        unsigned short h[8];
        for (int i = 0; i < 8; ++i) {
            int k = kbase + i;
            float v = 0.0f;
            if (jout < fout) {
                int jin;
                if (layer == 0) jin = (k < 3) ? k : ((k == 3) ? -2 : ((k == 4) ? -3 : -1));
                else            jin = INV[k];
                if (jin >= 0)       v = W[jin * fout + jout] * scale;
                else if (jin == -2) v = b[jout] * scale;
                else if (jin == -3) v = (layer == 6) ? 0.0f : UOFF;
            }
            _Float16 hv = (_Float16)v;
            h[i] = __builtin_bit_cast(unsigned short, hv);
        }
        unsigned short* dst = frags + frag * 512 + lane * 8;
        for (int i = 0; i < 8; ++i) dst[i] = h[i];
    }
    else if (tid < NFRAG * 64 + TABN) {
        int i = tid - NFRAG * 64;
        const float H = 1.0f / 32.0f;
        float x  = -TABR + (float)i * H;
        float t0 = tanhf(x);
        float t1 = tanhf(x + H);
        float MID = 0.5f * (1.0f + tanhf(TABR));
        float base = t0, delta = t1 - t0;
        if (i == 0)        { base = -MID; delta = t1 - base; }   // left clamp midpoint
        if (i == TABN - 2) { delta = MID - t0; }                 // right clamp midpoint
        unsigned short bb = __builtin_bit_cast(unsigned short, (_Float16)base);
        unsigned short dd = __builtin_bit_cast(unsigned short, (_Float16)delta);
        table[i] = (unsigned)bb | ((unsigned)dd << 16);          // unreplicated
    }
}

__device__ __forceinline__ unsigned int pkf16(float a, float b) {
    return __builtin_bit_cast(unsigned int, __builtin_amdgcn_cvt_pkrtz(a, b));
}
__device__ __forceinline__ f32x16 zf() {
    f32x16 v;
    #pragma unroll
    for (int i = 0; i < 16; ++i) v[i] = 0.0f;
    return v;
}

#define MFMA __builtin_amdgcn_mfma_f32_32x32x16_f16

// D holds table coords u; lookup tanh pairs into next-layer B fragment words
#define ACT(Da, Db, Bfx) do {                         \
    Bfx[0]  = tl2(Da[0],  Da[1]);                     \
    Bfx[1]  = tl2(Da[2],  Da[3]);                     \
    Bfx[2]  = tl2(Da[4],  Da[5]);                     \
    Bfx[3]  = tl2(Da[6],  Da[7]);                     \
    Bfx[4]  = tl2(Da[8],  Da[9]);                     \
    Bfx[5]  = tl2(Da[10], Da[11]);                    \
    Bfx[6]  = tl2(Da[12], Da[13]);                    \
    Bfx[7]  = tl2(Da[14], Da[15]);                    \
    Bfx[8]  = tl2(Db[0],  Db[1]);                     \
    Bfx[9]  = tl2(Db[2],  Db[3]);                     \
    Bfx[10] = PK11;                                   \
    Bfx[11] = 0u;                                     \
} while (0)

__global__ __launch_bounds__(512, 4) void mlp_mfma(const float* __restrict__ coords,
                                                   const unsigned short* __restrict__ frags,
                                                   const unsigned* __restrict__ gtab,
                                                   float* __restrict__ out, int npts)
{
    __shared__ __align__(16) unsigned short sf[NFRAG * 512];   // 35840 B
    __shared__ __align__(16) unsigned stab[TABN * TABREP];     // 28800 B
    {
        const u32x4* s1 = (const u32x4*)frags; u32x4* d1 = (u32x4*)sf;
        for (int i = threadIdx.x; i < NFRAG * 64; i += 512) d1[i] = s1[i];
        // replicate 32x from the unreplicated global table (L2-resident)
        for (int i = threadIdx.x; i < TABN * TABREP; i += 512) stab[i] = gtab[i >> 5];
    }
    __syncthreads();

    const int lane = threadIdx.x & 63;
    const int wid  = threadIdx.x >> 6;
    const int pA   = (blockIdx.x * 8 + wid) * 64 + (lane & 31);
    const int pB   = pA + 32;
    const bool vA = (pA < npts), vB = (pB < npts);

    float cA0 = 0.f, cA1 = 0.f, cA2 = 0.f, cB0 = 0.f, cB1 = 0.f, cB2 = 0.f;
    if (vA) { cA0 = coords[pA * 3]; cA1 = coords[pA * 3 + 1]; cA2 = coords[pA * 3 + 2]; }
    if (vB) { cB0 = coords[pB * 3]; cB1 = coords[pB * 3 + 1]; cB2 = coords[pB * 3 + 2]; }

    const unsigned int PK11 = pkf16(1.0f, 1.0f);
    const unsigned* __restrict__ tb = stab + (lane & 31);   // bank = lane&31 always
    const f32x16 CZ = zf();

    // table path: u = (x+3.5)*32 from MFMA; {base,delta} packed f16 in u32.
    // v_fma_mixlo/hi_f16: f32 fract times f16 delta (hi) plus f16 base (lo),
    // rounded to f16 straight into the selected half of the B-fragment word.
    auto tl2 = [&](float ua, float ub) -> unsigned {
        ua = __builtin_amdgcn_fmed3f(ua, 0.0f, UMAX);
        ub = __builtin_amdgcn_fmed3f(ub, 0.0f, UMAX);
        float fa = __builtin_amdgcn_fractf(ua);
        float fb = __builtin_amdgcn_fractf(ub);
        unsigned ea = tb[(unsigned)ua * TABREP];   // ds_read_b32, conflict-free
        unsigned eb = tb[(unsigned)ub * TABREP];
        unsigned r;
        asm("v_fma_mixlo_f16 %0, %1, %2, %2 op_sel:[0,1,0] op_sel_hi:[0,1,1]"
            : "=v"(r) : "v"(fa), "v"(ea));
        asm("v_fma_mixhi_f16 %0, %1, %2, %2 op_sel:[0,1,0] op_sel_hi:[0,1,1]"
            : "+v"(r) : "v"(fb), "v"(eb));
        return r;
    };

    unsigned int BfA[12], BfB[12];
    BfA[0] = pkf16(cA0, cA1); BfA[1] = pkf16(cA2, 1.0f);
    BfA[2] = pkf16(1.0f, 0.0f); BfA[3] = 0u;
    BfB[0] = pkf16(cB0, cB1); BfB[1] = pkf16(cB2, 1.0f);
    BfB[2] = pkf16(1.0f, 0.0f); BfB[3] = 0u;

    auto AF = [&](int f) -> f16x8 {
        return ((const f16x8*)sf)[f * 64 + lane];
    };
    auto BFx = [&](const unsigned (&B)[12], int c) -> f16x8 {
        u32x4 t = { B[4 * c + 0], B[4 * c + 1], B[4 * c + 2], B[4 * c + 3] };
        return __builtin_bit_cast(f16x8, t);
    };

    f16x8 F0, F1, F2, F3, F4, F5;

    // ---- layer 0 (K chunk 0: coords + bias + offset cols)
    F0 = AF(0); F1 = AF(1);
    {
        f32x16 D0 = MFMA(F0, BFx(BfA, 0), CZ, 0, 0, 0);
        f32x16 D1 = MFMA(F1, BFx(BfA, 0), CZ, 0, 0, 0);
        ACT(D0, D1, BfA);
    }
    {
        f32x16 D0 = MFMA(F0, BFx(BfB, 0), CZ, 0, 0, 0);
        f32x16 D1 = MFMA(F1, BFx(BfB, 0), CZ, 0, 0, 0);
        ACT(D0, D1, BfB);
    }

    // ---- hidden layers 1..5
    #pragma unroll
    for (int l = 1; l <= 5; ++l) {
        const int fb = 2 + (l - 1) * 6;
        F0 = AF(fb + 0); F1 = AF(fb + 1); F2 = AF(fb + 2);
        F3 = AF(fb + 3); F4 = AF(fb + 4); F5 = AF(fb + 5);
        {
            f16x8 B0 = BFx(BfA, 0), B1 = BFx(BfA, 1), B2 = BFx(BfA, 2);
            f32x16 D0 = MFMA(F0, B0, CZ, 0, 0, 0);
            D0 = MFMA(F1, B1, D0, 0, 0, 0);
            D0 = MFMA(F2, B2, D0, 0, 0, 0);
            f32x16 D1 = MFMA(F3, B0, CZ, 0, 0, 0);
            D1 = MFMA(F4, B1, D1, 0, 0, 0);
            D1 = MFMA(F5, B2, D1, 0, 0, 0);
            ACT(D0, D1, BfA);
        }
        {
            f16x8 B0 = BFx(BfB, 0), B1 = BFx(BfB, 1), B2 = BFx(BfB, 2);
            f32x16 D0 = MFMA(F0, B0, CZ, 0, 0, 0);
            D0 = MFMA(F1, B1, D0, 0, 0, 0);
            D0 = MFMA(F2, B2, D0, 0, 0, 0);
            f32x16 D1 = MFMA(F3, B0, CZ, 0, 0, 0);
            D1 = MFMA(F4, B1, D1, 0, 0, 0);
            D1 = MFMA(F5, B2, D1, 0, 0, 0);
            ACT(D0, D1, BfB);
        }
    }

    // ---- layer 6: [40] -> [3], true scale, no tanh. Rows 0..2 (lane<32).
    F0 = AF(32); F1 = AF(33); F2 = AF(34);
    {
        f32x16 D0 = MFMA(F0, BFx(BfA, 0), CZ, 0, 0, 0);
        D0 = MFMA(F1, BFx(BfA, 1), D0, 0, 0, 0);
        D0 = MFMA(F2, BFx(BfA, 2), D0, 0, 0, 0);
        if (lane < 32 && vA) {
            out[pA * 3 + 0] = D0[0];
            out[pA * 3 + 1] = D0[1];
            out[pA * 3 + 2] = D0[2];
        }
    }
    {
        f32x16 D0 = MFMA(F0, BFx(BfB, 0), CZ, 0, 0, 0);
        D0 = MFMA(F1, BFx(BfB, 1), D0, 0, 0, 0);
        D0 = MFMA(F2, BFx(BfB, 2), D0, 0, 0, 0);
        if (lane < 32 && vB) {
            out[pB * 3 + 0] = D0[0];
            out[pB * 3 + 1] = D0[1];
            out[pB * 3 + 2] = D0[2];
        }
    }
}

extern "C" void kernel_launch(void* const* d_in, const int* in_sizes, int n_in,
                              void* d_out, int out_size, void* d_ws, size_t ws_size,
                              hipStream_t stream)
{
    const float* coords = (const float*)d_in[0];
    const float* W0 = (const float*)d_in[1];  const float* b0 = (const float*)d_in[2];
    const float* W1 = (const float*)d_in[3];  const float* b1 = (const float*)d_in[4];
    const float* W2 = (const float*)d_in[5];  const float* b2 = (const float*)d_in[6];
    const float* W3 = (const float*)d_in[7];  const float* b3 = (const float*)d_in[8];
    const float* W4 = (const float*)d_in[9];  const float* b4 = (const float*)d_in[10];
    const float* W5 = (const float*)d_in[11]; const float* b5 = (const float*)d_in[12];
    const float* W6 = (const float*)d_in[13]; const float* b6 = (const float*)d_in[14];
    float* out = (float*)d_out;

    unsigned short* frags = (unsigned short*)d_ws;                      // 35840 B
    unsigned* table = (unsigned*)((char*)d_ws + NFRAG * 1024);          // 900 B

    const int npts = in_sizes[0] / 3;

    const int prep_threads = NFRAG * 64 + TABN;
    prep_frags<<<(prep_threads + 255) / 256, 256, 0, stream>>>(
        W0, b0, W1, b1, W2, b2, W3, b3, W4, b4, W5, b5, W6, b6, frags, table);

    const int blocks = (npts + 511) / 512;   // 512 points per block (8 waves x 64)
    mlp_mfma<<<blocks, 512, 0, stream>>>(coords, frags, table, out, npts);
}

// Round 8
// 111.647 us; speedup vs baseline: 1.0942x; 1.0645x over previous
//
#include <hip/hip_runtime.h>

// ============================================================================
// 7-layer MLP (3->40x6->3, tanh) via f16 MFMA + dual-pipe tanh:
//   words 0..5 of each 10-word activation pack (24/40 neurons): EXACT exp path
//     t = 1 - 2*rcp(1+2^y), weights pre-scaled by 2/ln2 -> MFMA emits y.
//     Runs on the quarter-rate trans pipe (8 cyc/wave-op).
//   words 6..9 (16/40 neurons): conflict-free LDS lerp table (32-replica,
//     bank == lane&31 always). Weights pre-scaled by 32 + offset column 112.
// r7 model: LDS pipe was the wall (1812 cyc/wave; 240 table reads = 77%).
// Split moves 60% of lookups to trans: LDS ~977 cyc/wave (52us) vs trans
// ~74k cyc/SIMD (31us) -> balanced ~60-70us.
// ws layout r7-proven (36.7 KB; r6's 64.6 KB overflowed ws -> poisoned the
// positive-saturation table tail -> absmax 0.19. Root-caused r7).
//
// MFMA layout contracts (gfx950 v_mfma_f32_32x32x16_f16), verified r3-r7:
//   A: row = lane&31, k = 8*(lane>>5)+i   B: col = lane&31, same k packing
//   D: col = lane&31, row = (reg&3) + 8*(reg>>2) + 4*(lane>>5)
// K-columns permuted (kappa) so D->B repack is in-lane. Identity verified:
// P := 4*(kap>>4) + ((kap&7)>>1) == the Bf word index a neuron is packed
// into, for all 40 neurons -> prep's per-row path classification (P < SEXP)
// exactly matches ACT's static word split.
// ============================================================================

typedef _Float16 f16x8 __attribute__((ext_vector_type(8)));
typedef float    f32x16 __attribute__((ext_vector_type(16)));
typedef unsigned int u32x4 __attribute__((ext_vector_type(4)));

#define NFRAG  35        // L0: 2, L1..5: 6 each, L6: 3
#define TABN   225       // entries, domain [-3.5, 3.5], h = 1/32
#define TABREP 32        // LDS replication -> bank = lane&31, conflict-free
#define SEXP   6         // Bf words 0..5 (24 rows/layer) via exp path
#define INVH   32.0f
#define UOFF   112.0f    // 3.5*32, exact in f16
#define UMAX   223.999f
#define TABR   3.5f
#define EXPSC  2.8853900817779268f   // 2/ln(2)

// k-slot -> input neuron; -2 = bias, -3 = offset const, -1 = zero pad
__constant__ int INV[48] = {
     0,  1,  2,  3,   8,  9, 10, 11,   4,  5,  6,  7,  12, 13, 14, 15,
    16, 17, 18, 19,  24, 25, 26, 27,  20, 21, 22, 23,  28, 29, 30, 31,
    32, 33, 34, 35,  -1, -1, -1, -1,  36, 37, 38, 39,  -2, -3, -1, -1 };

// output neuron j -> k-slot (kappa); P(j) = 4*(kap>>4) + ((kap&7)>>1) = word
__constant__ int KAP[40] = {
     0,  1,  2,  3,   8,  9, 10, 11,   4,  5,  6,  7,  12, 13, 14, 15,
    16, 17, 18, 19,  24, 25, 26, 27,  20, 21, 22, 23,  28, 29, 30, 31,
    32, 33, 34, 35,  40, 41, 42, 43 };

__global__ void prep_frags(const float* __restrict__ W0, const float* __restrict__ b0,
                           const float* __restrict__ W1, const float* __restrict__ b1,
                           const float* __restrict__ W2, const float* __restrict__ b2,
                           const float* __restrict__ W3, const float* __restrict__ b3,
                           const float* __restrict__ W4, const float* __restrict__ b4,
                           const float* __restrict__ W5, const float* __restrict__ b5,
                           const float* __restrict__ W6, const float* __restrict__ b6,
                           unsigned short* __restrict__ frags,
                           unsigned* __restrict__ table)
{
    int tid = blockIdx.x * 256 + threadIdx.x;

    if (tid < NFRAG * 64) {
        int frag = tid >> 6, lane = tid & 63;

        int layer, mt, ch;
        if (frag < 2)       { layer = 0; mt = frag; ch = 0; }
        else if (frag < 32) { int t = frag - 2; layer = 1 + t / 6; int r = t % 6; mt = r / 3; ch = r % 3; }
        else                { layer = 6; mt = 0; ch = frag - 32; }

        const float* Ws[7] = { W0, W1, W2, W3, W4, W5, W6 };
        const float* bs[7] = { b0, b1, b2, b3, b4, b5, b6 };
        const float* W = Ws[layer];
        const float* b = bs[layer];
        const int fout = (layer == 6) ? 3 : 40;

        int jout  = mt * 32 + (lane & 31);
        int kbase = ch * 16 + (lane >> 5) * 8;

        unsigned short h[8];
        for (int i = 0; i < 8; ++i) {
            int k = kbase + i;
            float v = 0.0f;
            if (jout < fout) {
                int jin;
                if (layer == 0) jin = (k < 3) ? k : ((k == 3) ? -2 : ((k == 4) ? -3 : -1));
                else            jin = INV[k];
                bool ex = false;
                if (layer < 6) {
                    int kp = KAP[jout];
                    int P = 4 * (kp >> 4) + ((kp & 7) >> 1);   // == Bf word index
                    ex = (P < SEXP);
                }
                float scale = (layer == 6) ? 1.0f : (ex ? EXPSC : INVH);
                if (jin >= 0)       v = W[jin * fout + jout] * scale;
                else if (jin == -2) v = b[jout] * scale;
                else if (jin == -3) v = (layer == 6 || ex) ? 0.0f : UOFF;
            }
            _Float16 hv = (_Float16)v;
            h[i] = __builtin_bit_cast(unsigned short, hv);
        }
        unsigned short* dst = frags + frag * 512 + lane * 8;
        for (int i = 0; i < 8; ++i) dst[i] = h[i];
    }
    else if (tid < NFRAG * 64 + TABN) {
        int i = tid - NFRAG * 64;
        const float H = 1.0f / 32.0f;
        float x  = -TABR + (float)i * H;
        float t0 = tanhf(x);
        float t1 = tanhf(x + H);
        float MID = 0.5f * (1.0f + tanhf(TABR));
        float base = t0, delta = t1 - t0;
        if (i == 0)        { base = -MID; delta = t1 - base; }   // left clamp midpoint
        if (i == TABN - 2) { delta = MID - t0; }                 // right clamp midpoint
        unsigned short bb = __builtin_bit_cast(unsigned short, (_Float16)base);
        unsigned short dd = __builtin_bit_cast(unsigned short, (_Float16)delta);
        table[i] = (unsigned)bb | ((unsigned)dd << 16);          // unreplicated, 900 B
    }
}

__device__ __forceinline__ unsigned int pkf16(float a, float b) {
    return __builtin_bit_cast(unsigned int, __builtin_amdgcn_cvt_pkrtz(a, b));
}
__device__ __forceinline__ f32x16 zf() {
    f32x16 v;
    #pragma unroll
    for (int i = 0; i < 16; ++i) v[i] = 0.0f;
    return v;
}
__device__ __forceinline__ float exp2_fast(float y) {
#if __has_builtin(__builtin_amdgcn_exp2f)
    return __builtin_amdgcn_exp2f(y);
#else
    float e;
    asm("v_exp_f32 %0, %1" : "=v"(e) : "v"(y));
    return e;
#endif
}

#define MFMA __builtin_amdgcn_mfma_f32_32x32x16_f16

// words 0..5: exp path (y = 2x/ln2 from MFMA); words 6..9: table path
#define ACT(Da, Db, Bfx) do {                         \
    Bfx[0]  = pkf16(te(Da[0]),  te(Da[1]));           \
    Bfx[1]  = pkf16(te(Da[2]),  te(Da[3]));           \
    Bfx[2]  = pkf16(te(Da[4]),  te(Da[5]));           \
    Bfx[3]  = pkf16(te(Da[6]),  te(Da[7]));           \
    Bfx[4]  = pkf16(te(Da[8]),  te(Da[9]));           \
    Bfx[5]  = pkf16(te(Da[10]), te(Da[11]));          \
    Bfx[6]  = tl2(Da[12], Da[13]);                    \
    Bfx[7]  = tl2(Da[14], Da[15]);                    \
    Bfx[8]  = tl2(Db[0],  Db[1]);                     \
    Bfx[9]  = tl2(Db[2],  Db[3]);                     \
    Bfx[10] = PK11;                                   \
    Bfx[11] = 0u;                                     \
} while (0)

__global__ __launch_bounds__(512, 4) void mlp_mfma(const float* __restrict__ coords,
                                                   const unsigned short* __restrict__ frags,
                                                   const unsigned* __restrict__ gtab,
                                                   float* __restrict__ out, int npts)
{
    __shared__ __align__(16) unsigned short sf[NFRAG * 512];   // 35840 B
    __shared__ __align__(16) unsigned stab[TABN * TABREP];     // 28800 B
    {
        const u32x4* s1 = (const u32x4*)frags; u32x4* d1 = (u32x4*)sf;
        for (int i = threadIdx.x; i < NFRAG * 64; i += 512) d1[i] = s1[i];
        // replicate 32x from the unreplicated global table (L2-resident)
        for (int i = threadIdx.x; i < TABN * TABREP; i += 512) stab[i] = gtab[i >> 5];
    }
    __syncthreads();

    const int lane = threadIdx.x & 63;
    const int wid  = threadIdx.x >> 6;
    const int pA   = (blockIdx.x * 8 + wid) * 64 + (lane & 31);
    const int pB   = pA + 32;
    const bool vA = (pA < npts), vB = (pB < npts);

    float cA0 = 0.f, cA1 = 0.f, cA2 = 0.f, cB0 = 0.f, cB1 = 0.f, cB2 = 0.f;
    if (vA) { cA0 = coords[pA * 3]; cA1 = coords[pA * 3 + 1]; cA2 = coords[pA * 3 + 2]; }
    if (vB) { cB0 = coords[pB * 3]; cB1 = coords[pB * 3 + 1]; cB2 = coords[pB * 3 + 2]; }

    const unsigned int PK11 = pkf16(1.0f, 1.0f);
    const unsigned* __restrict__ tb = stab + (lane & 31);   // bank = lane&31 always
    const f32x16 CZ = zf();

    // table path: u = (x+3.5)*32 from MFMA; {base,delta} packed f16 in u32.
    auto tl2 = [&](float ua, float ub) -> unsigned {
        ua = __builtin_amdgcn_fmed3f(ua, 0.0f, UMAX);
        ub = __builtin_amdgcn_fmed3f(ub, 0.0f, UMAX);
        float fa = __builtin_amdgcn_fractf(ua);
        float fb = __builtin_amdgcn_fractf(ub);
        unsigned ea = tb[(unsigned)ua * TABREP];   // ds_read_b32, conflict-free
        unsigned eb = tb[(unsigned)ub * TABREP];
        unsigned r;
        asm("v_fma_mixlo_f16 %0, %1, %2, %2 op_sel:[0,1,0] op_sel_hi:[0,1,1]"
            : "=v"(r) : "v"(fa), "v"(ea));
        asm("v_fma_mixhi_f16 %0, %1, %2, %2 op_sel:[0,1,0] op_sel_hi:[0,1,1]"
            : "+v"(r) : "v"(fb), "v"(eb));
        return r;
    };
    // exp path: y = 2x/ln2 from MFMA; tanh = 1 - 2/(1+2^y). Exact, no clamp:
    // 2^y -> inf gives rcp->0 -> +1; 2^y -> 0 gives rcp(1)=1 -> -1.
    auto te = [&](float y) -> float {
        float e = exp2_fast(y);
        float r = __builtin_amdgcn_rcpf(e + 1.0f);
        return __builtin_fmaf(-2.0f, r, 1.0f);
    };

    unsigned int BfA[12], BfB[12];
    BfA[0] = pkf16(cA0, cA1); BfA[1] = pkf16(cA2, 1.0f);
    BfA[2] = pkf16(1.0f, 0.0f); BfA[3] = 0u;
    BfB[0] = pkf16(cB0, cB1); BfB[1] = pkf16(cB2, 1.0f);
    BfB[2] = pkf16(1.0f, 0.0f); BfB[3] = 0u;

    auto AF = [&](int f) -> f16x8 {
        return ((const f16x8*)sf)[f * 64 + lane];
    };
    auto BFx = [&](const unsigned (&B)[12], int c) -> f16x8 {
        u32x4 t = { B[4 * c + 0], B[4 * c + 1], B[4 * c + 2], B[4 * c + 3] };
        return __builtin_bit_cast(f16x8, t);
    };

    f16x8 F0, F1, F2, F3, F4, F5;

    // ---- layer 0 (K chunk 0: coords + bias + offset cols)
    F0 = AF(0); F1 = AF(1);
    {
        f32x16 D0 = MFMA(F0, BFx(BfA, 0), CZ, 0, 0, 0);
        f32x16 D1 = MFMA(F1, BFx(BfA, 0), CZ, 0, 0, 0);
        ACT(D0, D1, BfA);
    }
    {
        f32x16 D0 = MFMA(F0, BFx(BfB, 0), CZ, 0, 0, 0);
        f32x16 D1 = MFMA(F1, BFx(BfB, 0), CZ, 0, 0, 0);
        ACT(D0, D1, BfB);
    }

    // ---- hidden layers 1..5
    #pragma unroll
    for (int l = 1; l <= 5; ++l) {
        const int fb = 2 + (l - 1) * 6;
        F0 = AF(fb + 0); F1 = AF(fb + 1); F2 = AF(fb + 2);
        F3 = AF(fb + 3); F4 = AF(fb + 4); F5 = AF(fb + 5);
        {
            f16x8 B0 = BFx(BfA, 0), B1 = BFx(BfA, 1), B2 = BFx(BfA, 2);
            f32x16 D0 = MFMA(F0, B0, CZ, 0, 0, 0);
            D0 = MFMA(F1, B1, D0, 0, 0, 0);
            D0 = MFMA(F2, B2, D0, 0, 0, 0);
            f32x16 D1 = MFMA(F3, B0, CZ, 0, 0, 0);
            D1 = MFMA(F4, B1, D1, 0, 0, 0);
            D1 = MFMA(F5, B2, D1, 0, 0, 0);
            ACT(D0, D1, BfA);
        }
        {
            f16x8 B0 = BFx(BfB, 0), B1 = BFx(BfB, 1), B2 = BFx(BfB, 2);
            f32x16 D0 = MFMA(F0, B0, CZ, 0, 0, 0);
            D0 = MFMA(F1, B1, D0, 0, 0, 0);
            D0 = MFMA(F2, B2, D0, 0, 0, 0);
            f32x16 D1 = MFMA(F3, B0, CZ, 0, 0, 0);
            D1 = MFMA(F4, B1, D1, 0, 0, 0);
            D1 = MFMA(F5, B2, D1, 0, 0, 0);
            ACT(D0, D1, BfB);
        }
    }

    // ---- layer 6: [40] -> [3], true scale, no tanh. Rows 0..2 (lane<32).
    F0 = AF(32); F1 = AF(33); F2 = AF(34);
    {
        f32x16 D0 = MFMA(F0, BFx(BfA, 0), CZ, 0, 0, 0);
        D0 = MFMA(F1, BFx(BfA, 1), D0, 0, 0, 0);
        D0 = MFMA(F2, BFx(BfA, 2), D0, 0, 0, 0);
        if (lane < 32 && vA) {
            out[pA * 3 + 0] = D0[0];
            out[pA * 3 + 1] = D0[1];
            out[pA * 3 + 2] = D0[2];
        }
    }
    {
        f32x16 D0 = MFMA(F0, BFx(BfB, 0), CZ, 0, 0, 0);
        D0 = MFMA(F1, BFx(BfB, 1), D0, 0, 0, 0);
        D0 = MFMA(F2, BFx(BfB, 2), D0, 0, 0, 0);
        if (lane < 32 && vB) {
            out[pB * 3 + 0] = D0[0];
            out[pB * 3 + 1] = D0[1];
            out[pB * 3 + 2] = D0[2];
        }
    }
}

extern "C" void kernel_launch(void* const* d_in, const int* in_sizes, int n_in,
                              void* d_out, int out_size, void* d_ws, size_t ws_size,
                              hipStream_t stream)
{
    const float* coords = (const float*)d_in[0];
    const float* W0 = (const float*)d_in[1];  const float* b0 = (const float*)d_in[2];
    const float* W1 = (const float*)d_in[3];  const float* b1 = (const float*)d_in[4];
    const float* W2 = (const float*)d_in[5];  const float* b2 = (const float*)d_in[6];
    const float* W3 = (const float*)d_in[7];  const float* b3 = (const float*)d_in[8];
    const float* W4 = (const float*)d_in[9];  const float* b4 = (const float*)d_in[10];
    const float* W5 = (const float*)d_in[11]; const float* b5 = (const float*)d_in[12];
    const float* W6 = (const float*)d_in[13]; const float* b6 = (const float*)d_in[14];
    float* out = (float*)d_out;

    unsigned short* frags = (unsigned short*)d_ws;                      // 35840 B
    unsigned* table = (unsigned*)((char*)d_ws + NFRAG * 1024);          // 900 B

    const int npts = in_sizes[0] / 3;

    const int prep_threads = NFRAG * 64 + TABN;
    prep_frags<<<(prep_threads + 255) / 256, 256, 0, stream>>>(
        W0, b0, W1, b1, W2, b2, W3, b3, W4, b4, W5, b5, W6, b6, frags, table);

    const int blocks = (npts + 511) / 512;   // 512 points per block (8 waves x 64)
    mlp_mfma<<<blocks, 512, 0, stream>>>(coords, frags, table, out, npts);
}